// Round 5
// baseline (1435.908 us; speedup 1.0000x reference)
//
#include <hip/hip_runtime.h>

// ---------------------------------------------------------------------------
// CasualGraph on MI355X. 3 layers of source = T^T (T x); x = LN(source+x0);
// then per-hyperedge mean of final pre-norm source, global max over edges.
// bf16 MFMA 16x16x32, fp32 accumulate.
//
// R5 design: FULL-K GEMMs with fused epilogues (no split-K partials).
//   M = 256 = BM -> every block owns complete output columns, so:
//     gemm1: writes bf16 tt directly          (was: 32MB P wr + 32MB rd + cvt)
//     gemm2: fuses +x0 residual + LayerNorm   (was: P round-trip + ln pass)
//     gemmE: writes f32 sums directly
//   BN=32 (BN=16 for E-GEMM) -> grid 256 = 1 block/CU, full K=8192 per block.
//   B matrix still streamed exactly once from HBM (128 MB floor); A re-staged
//   per block (4 MB/CU) hits XCD L2 (same k-slab across co-resident blocks).
//   K-loop: R4-proven double-buffered __syncthreads schedule, 8 waves,
//   2 waves/SIMD, global_load_lds(16B) with XOR-swizzled global index.
// ---------------------------------------------------------------------------

typedef __bf16 bf16;
typedef __bf16 bf16x8 __attribute__((ext_vector_type(8)));
typedef float f32x4 __attribute__((ext_vector_type(4)));

__device__ __forceinline__ void gld_lds16(const bf16* g, bf16* l) {
  __builtin_amdgcn_global_load_lds(
      (const __attribute__((address_space(1))) unsigned int*)g,
      (__attribute__((address_space(3))) unsigned int*)l, 16, 0, 0);
}

// ---------------------------------------------------------------------------
// C[m][n] = sum_k A[m][k]*B[n][k], m<256, full K. A,B bf16 K-contiguous.
// BM=256, BN=32 (8 waves as 4Mx2N, wave tile 64x16) or BN=16 (8Mx1N, 32x16).
// LDS row = 128 B = 8 x 16-B chunks; LDS[row][c] holds global chunk c^(row&7)
// (swizzle on the GLOBAL index since global_load_lds scatters lane i ->
//  base + 16*i). Per k-step each wave stages 4 A wave-loads; waves w<BN/8
// stage 1 B wave-load. Double buffer: stage(next) -> compute(cur) -> sync.
//
// EPI: 0 = bf16 store; 1 = fused residual+LayerNorm -> bf16; 2 = f32 store.
// For EPI=1 each block holds ALL 256 d-values of its 32 columns: cross-wave
// LDS reduce gives per-column mu/rsigma, then normalize+gamma/beta in regs.
// ---------------------------------------------------------------------------
template <int BN, int EPI>
__global__ __launch_bounds__(512) void gemm_full(
    const bf16* __restrict__ A, const bf16* __restrict__ B,
    void* __restrict__ out, const float* __restrict__ x0t,
    const float* __restrict__ gamma, const float* __restrict__ beta,
    int N, int K) {
  constexpr int BM = 256, BK = 64;
  constexpr int NWN = (BN == 32) ? 2 : 1;  // N-wave groups
  constexpr int NWM = 8 / NWN;             // M-wave groups (4 or 8)
  constexpr int WM = BM / NWM;             // 64 or 32
  constexpr int TM = WM / 16;              // 4 or 2
  constexpr int NSH = (NWN == 2) ? 1 : 0;

  __shared__ __align__(16) bf16 As[2][BM * BK];  // 32 KB each
  __shared__ __align__(16) bf16 Bs[2][BN * BK];  // 4 or 2 KB each

  const int t = threadIdx.x, w = t >> 6, l = t & 63;
  // staging: one wave-load covers 8 rows x 128 B; lane l -> row l>>3,
  // LDS chunk l&7, which must receive global chunk (l&7)^(row&7)=(l&7)^(l>>3)
  const int srow = l >> 3;
  const int schunk = (l & 7) ^ srow;
  const int n0 = blockIdx.x * BN;

  const bf16* gA = A + (size_t)(w * 8 + srow) * K + schunk * 8;
  const bf16* gB = B + (size_t)(n0 + w * 8 + srow) * K + schunk * 8;

  auto stage = [&](int kk, int buf) {
    const size_t ko = (size_t)kk * BK;
#pragma unroll
    for (int q = 0; q < 4; ++q)
      gld_lds16(gA + (size_t)(q * 64) * K + ko,
                &As[buf][(q * 64 + w * 8) * BK]);
    if (w < BN / 8) gld_lds16(gB + ko, &Bs[buf][(w * 8) * BK]);
  };

  const int lm = l & 15, kq = l >> 4;
  const int mw = w >> NSH, nw = w & (NWN - 1);
  const int wm = mw * WM, wn = nw * 16;

  f32x4 acc[TM] = {};
  const int nk = K / BK;

  stage(0, 0);
  __syncthreads();

  for (int kk = 0; kk < nk; ++kk) {
    const int buf = kk & 1;
    if (kk + 1 < nk) stage(kk + 1, buf ^ 1);  // async into other buffer
#pragma unroll
    for (int ks = 0; ks < 2; ++ks) {
      const int csw = ((ks * 4 + kq) ^ (lm & 7)) * 8;  // row&7 == lm&7
      const bf16x8 bfr = *(const bf16x8*)(&Bs[buf][(wn + lm) * BK + csw]);
      bf16x8 af[TM];
#pragma unroll
      for (int i = 0; i < TM; ++i)
        af[i] = *(const bf16x8*)(&As[buf][(wm + i * 16 + lm) * BK + csw]);
#pragma unroll
      for (int i = 0; i < TM; ++i)
        acc[i] = __builtin_amdgcn_mfma_f32_16x16x32_bf16(af[i], bfr, acc[i],
                                                         0, 0, 0);
    }
    __syncthreads();  // drains vmcnt: buf^1 fully written, reads complete
  }

  // epilogue: C/D layout col = lane&15, row = kq*4 + r
  const int col = n0 + wn + lm;
  if constexpr (EPI == 0) {
    bf16* O = (bf16*)out;
#pragma unroll
    for (int i = 0; i < TM; ++i) {
      const int mrow = wm + i * 16 + kq * 4;
#pragma unroll
      for (int r = 0; r < 4; ++r)
        O[(size_t)(mrow + r) * N + col] = (bf16)acc[i][r];
    }
  } else if constexpr (EPI == 2) {
    float* O = (float*)out;
#pragma unroll
    for (int i = 0; i < TM; ++i) {
      const int mrow = wm + i * 16 + kq * 4;
#pragma unroll
      for (int r = 0; r < 4; ++r)
        O[(size_t)(mrow + r) * N + col] = acc[i][r];
    }
  } else {
    // fused residual + LayerNorm over d (the M dim; 256 values per column)
    __shared__ float lnS[NWM][4][32], lnQ[NWM][4][32];
    __shared__ float MU[32], RS[32];
    float v[TM][4];
    float s = 0.f, s2 = 0.f;
#pragma unroll
    for (int i = 0; i < TM; ++i) {
      const int mrow = wm + i * 16 + kq * 4;
#pragma unroll
      for (int r = 0; r < 4; ++r) {
        const float vv = acc[i][r] + x0t[(size_t)(mrow + r) * N + col];
        v[i][r] = vv;
        s += vv;
        s2 += vv * vv;
      }
    }
    lnS[mw][kq][wn + lm] = s;
    lnQ[mw][kq][wn + lm] = s2;
    __syncthreads();
    if (t < 32) {
      float a = 0.f, b = 0.f;
#pragma unroll
      for (int m2 = 0; m2 < NWM; ++m2)
#pragma unroll
        for (int k2 = 0; k2 < 4; ++k2) {
          a += lnS[m2][k2][t];
          b += lnQ[m2][k2][t];
        }
      const float mu = a * (1.0f / 256.0f);
      MU[t] = mu;
      RS[t] = rsqrtf(b * (1.0f / 256.0f) - mu * mu + 1e-5f);
    }
    __syncthreads();
    const float mu = MU[wn + lm], rs = RS[wn + lm];
    bf16* O = (bf16*)out;
#pragma unroll
    for (int i = 0; i < TM; ++i) {
      const int mrow = wm + i * 16 + kq * 4;
#pragma unroll
      for (int r = 0; r < 4; ++r) {
        const int d = mrow + r;
        O[(size_t)d * N + col] =
            (bf16)((v[i][r] - mu) * rs * gamma[d] + beta[d]);
      }
    }
  }
}

// ---------------------------------------------------------------------------
// 64x64 LDS tile transpose/convert: src [R][C] f32 ->
//   cpy [R][C] bf16 (opt), trb [C][R] bf16 (opt), trf [C][R] f32 (opt),
//   cnt[c] += column sums (opt; used to fuse hyperedge counts into the
//   H transpose - fp32 adds of 0/1 integers are exact & order-independent).
// ---------------------------------------------------------------------------
__global__ __launch_bounds__(256) void transpose_conv(
    const float* __restrict__ src, int R, int C, bf16* __restrict__ cpy,
    bf16* __restrict__ trb, float* __restrict__ trf, float* __restrict__ cnt) {
  __shared__ float tile[64][65];
  __shared__ float cs[4][64];
  const int t = threadIdx.x;
  const int col = t & 63, rb4 = t >> 6;
  const int r0 = blockIdx.y * 64, c0 = blockIdx.x * 64;
  float csum = 0.f;
#pragma unroll
  for (int rr = 0; rr < 64; rr += 4) {
    const int row = rr + rb4;
    const float v = src[(size_t)(r0 + row) * C + c0 + col];
    tile[row][col] = v;
    csum += v;
    if (cpy) cpy[(size_t)(r0 + row) * C + c0 + col] = (bf16)v;
  }
  __syncthreads();
  if (cnt) {
    cs[rb4][col] = csum;
    __syncthreads();
    if (rb4 == 0)
      atomicAdd(&cnt[c0 + col], cs[0][col] + cs[1][col] + cs[2][col] + cs[3][col]);
  }
#pragma unroll
  for (int rr = 0; rr < 64; rr += 4) {
    const int row = rr + rb4;
    const float v = tile[col][row];
    const size_t di = (size_t)(c0 + row) * R + r0 + col;
    if (trb) trb[di] = (bf16)v;
    if (trf) trf[di] = v;
  }
}

// ---------------------------------------------------------------------------
// out[d] = max_e (sum_{s<S} P[s][d][e]) / cnt[e]
// ---------------------------------------------------------------------------
__global__ __launch_bounds__(256) void final_max(const float* __restrict__ P,
                                                 const float* __restrict__ cnt,
                                                 float* __restrict__ out,
                                                 int S) {
  constexpr size_t MN = (size_t)256 * 4096;
  const int d = blockIdx.x;
  float m = -3.4e38f;
  for (int e = threadIdx.x; e < 4096; e += 256) {
    const size_t idx = (size_t)d * 4096 + e;
    float s = 0.f;
    for (int z = 0; z < S; ++z) s += P[z * MN + idx];
    m = fmaxf(m, s / cnt[e]);
  }
  __shared__ float red[256];
  red[threadIdx.x] = m;
  __syncthreads();
  for (int k = 128; k > 0; k >>= 1) {
    if (threadIdx.x < k)
      red[threadIdx.x] = fmaxf(red[threadIdx.x], red[threadIdx.x + k]);
    __syncthreads();
  }
  if (threadIdx.x == 0) out[d] = red[0];
}

// ---------------------------------------------------------------------------
extern "C" void kernel_launch(void* const* d_in, const int* in_sizes, int n_in,
                              void* d_out, int out_size, void* d_ws,
                              size_t ws_size, hipStream_t stream) {
  const float* x0 = (const float*)d_in[0];    // [8192][256]
  const float* T = (const float*)d_in[1];     // [8192][8192]
  const float* H = (const float*)d_in[2];     // [8192][4096]
  const float* gamma = (const float*)d_in[3]; // [256]
  const float* beta = (const float*)d_in[4];  // [256]

  constexpr int Nn = 8192, E = 4096, D = 256, K = 8192;

  char* w = (char*)d_ws;
  size_t off = 0;
  auto carve = [&](size_t bytes) {
    char* p = w + off;
    off += (bytes + 255) & ~(size_t)255;
    return p;
  };
  bf16* Tb = (bf16*)carve((size_t)Nn * Nn * 2);
  bf16* Tt = (bf16*)carve((size_t)Nn * Nn * 2);
  bf16* Htb = (bf16*)carve((size_t)E * Nn * 2);
  float* x0t = (float*)carve((size_t)D * Nn * 4);
  bf16* Xt = (bf16*)carve((size_t)D * Nn * 2);
  bf16* tt = (bf16*)carve((size_t)D * Nn * 2);
  bf16* stb = (bf16*)carve((size_t)D * Nn * 2);
  float* cnts = (float*)carve((size_t)E * 4);
  float* sums = (float*)carve((size_t)D * E * 4);  // 4 MB final sums

  if (off > ws_size) {  // workspace too small: fail loudly (out = 0)
    hipMemsetAsync(d_out, 0, (size_t)out_size * 4, stream);
    return;
  }

  // one-time layout prep (counts fused into the H transpose)
  hipMemsetAsync(cnts, 0, (size_t)E * 4, stream);
  transpose_conv<<<dim3(128, 128), 256, 0, stream>>>(T, Nn, Nn, Tb, Tt, nullptr,
                                                     nullptr);
  transpose_conv<<<dim3(64, 128), 256, 0, stream>>>(H, Nn, E, nullptr, Htb,
                                                    nullptr, cnts);
  transpose_conv<<<dim3(4, 128), 256, 0, stream>>>(x0, Nn, D, nullptr, Xt, x0t,
                                                   nullptr);

  for (int layer = 0; layer < 3; ++layer) {
    // tt[d][j] = sum_k Xt[d][k] * Tb[j][k]   (direct bf16 out)
    gemm_full<32, 0><<<Nn / 32, 512, 0, stream>>>(Xt, Tb, tt, nullptr, nullptr,
                                                  nullptr, Nn, K);
    if (layer < 2) {
      // Xt[d][i] = LN_d( sum_j tt[d][j]*Tt[i][j] + x0t[d][i] )  (fused)
      gemm_full<32, 1><<<Nn / 32, 512, 0, stream>>>(tt, Tt, Xt, x0t, gamma,
                                                    beta, Nn, K);
    } else {
      // stb[d][i] = sum_j tt[d][j]*Tt[i][j]   (pre-norm source, bf16)
      gemm_full<32, 0><<<Nn / 32, 512, 0, stream>>>(tt, Tt, stb, nullptr,
                                                    nullptr, nullptr, Nn, K);
    }
  }

  // sums[d][e] = sum_i stb[d][i] * Htb[e][i]   (direct f32 out)
  gemm_full<16, 2><<<E / 16, 512, 0, stream>>>(stb, Htb, sums, nullptr, nullptr,
                                               nullptr, E, K);
  final_max<<<D, 256, 0, stream>>>(sums, cnts, (float*)d_out, 1);
}

// Round 6
// 1013.687 us; speedup vs baseline: 1.4165x; 1.4165x over previous
//
#include <hip/hip_runtime.h>

// ---------------------------------------------------------------------------
// CasualGraph on MI355X. 3 layers of source = T^T (T x); x = LN(source+x0);
// then per-hyperedge mean of final pre-norm source, global max over edges.
// bf16 MFMA 16x16x32, fp32 accumulate.
//
// R6 design (revert R5; attack GEMM occupancy):
//   BM = 256 = M  -> B matrix read exactly once (128 MB floor per GEMM)
//   BN = 64, split-K=4 -> grid 512 = 2 blocks/CU. LDS/block = 80 KB
//   (As 32K + Bs 8K, double-buffered) -> exactly 2 resident blocks.
//   RATIONALE: each K-step ends in __syncthreads (vmcnt-0 drain of the HBM
//   stage, ~1600cy tail). At 1 block/CU (R4: 96 KB LDS, grid 256) the whole
//   CU idles through the drain. 2 co-resident blocks overlap each other's
//   drains implicitly (m114/m97 structure: ~3 blk/CU was the measured-good
//   config). In-loop pipelining levers (R0/R1) measured ~nil - the overlap
//   must come from co-residency, not scheduling.
//   BK = 64 -> every staged request is a full 128-B line.
//   512 threads = 8 waves (4Mx2N), wave tile 64x32.
// ---------------------------------------------------------------------------

typedef __bf16 bf16;
typedef __bf16 bf16x8 __attribute__((ext_vector_type(8)));
typedef float f32x4 __attribute__((ext_vector_type(4)));

__device__ __forceinline__ void gld_lds16(const bf16* g, bf16* l) {
  __builtin_amdgcn_global_load_lds(
      (const __attribute__((address_space(1))) unsigned int*)g,
      (__attribute__((address_space(3))) unsigned int*)l, 16, 0, 0);
}

// ---------------------------------------------------------------------------
// P[z][m][n] = sum_{k in split z} A[m][k]*B[n][k].  A,B bf16 K-contiguous.
// BM=256 (=M), BN=64, BK=64. 512 threads = 8 waves (4 M x 2 N), wave tile
// 64x32 (TM=4, TN=2).
// LDS row = 128 B = 8 x 16-B chunks; LDS[row][c] holds global chunk c^(row&7)
// (swizzle applied on the GLOBAL index since global_load_lds scatters
//  lane i -> base + 16*i). ds_read fragments then hit 8 bank-groups (2-way).
// K-loop: double buffer; issue next tile's global_load_lds, compute current,
// __syncthreads() (drains vmcnt -> buf^1 fully written, all reads done).
// ---------------------------------------------------------------------------
template <int BN>
__global__ __launch_bounds__(512) void gemm_bt(const bf16* __restrict__ A,
                                               const bf16* __restrict__ B,
                                               float* __restrict__ P,
                                               int N, int K, int Ks) {
  constexpr int BM = 256, BK = 64;
  constexpr int WM = 64, WN = BN / 2;
  constexpr int TM = WM / 16, TN = WN / 16;          // 4, BN/32
  constexpr int QA = BM / 64, QB = BN / 64;          // 4, BN/64 per wave

  __shared__ __align__(16) bf16 As[2][BM * BK];  // 32 KB each
  __shared__ __align__(16) bf16 Bs[2][BN * BK];  // 8 KB each (BN=64)

  const int t = threadIdx.x, w = t >> 6, l = t & 63;
  // staging: one wave-load covers 8 rows x 128 B; lane l -> row l>>3,
  // LDS chunk l&7, which must receive global chunk (l&7)^(row&7)=(l&7)^(l>>3)
  const int srow = l >> 3;
  const int schunk = (l & 7) ^ srow;
  const int n0 = blockIdx.x * BN;
  const int kbase = blockIdx.z * Ks;

  const bf16* gA = A + (size_t)(w * 8 + srow) * K + kbase + schunk * 8;
  const bf16* gB = B + (size_t)(n0 + w * 8 + srow) * K + kbase + schunk * 8;

  auto stage = [&](int kk, int buf) {
    const size_t ko = (size_t)kk * BK;
#pragma unroll
    for (int q = 0; q < QA; ++q)
      gld_lds16(gA + (size_t)(q * 64) * K + ko,
                &As[buf][(q * 64 + w * 8) * BK]);
#pragma unroll
    for (int q = 0; q < QB; ++q)
      gld_lds16(gB + (size_t)(q * 64) * K + ko,
                &Bs[buf][(q * 64 + w * 8) * BK]);
  };

  const int lm = l & 15, kq = l >> 4;
  const int wm = (w >> 1) * WM;  // 0,64,128,192
  const int wn = (w & 1) * WN;   // 0,32

  f32x4 acc[TM][TN] = {};
  const int nk = Ks / BK;

  stage(0, 0);
  __syncthreads();

  for (int kk = 0; kk < nk; ++kk) {
    const int buf = kk & 1;
    if (kk + 1 < nk) stage(kk + 1, buf ^ 1);  // async into other buffer
#pragma unroll
    for (int ks = 0; ks < 2; ++ks) {
      const int csw = ((ks * 4 + kq) ^ (lm & 7)) * 8;  // row&7 == lm&7
      bf16x8 af[TM], bfr[TN];
#pragma unroll
      for (int i = 0; i < TM; ++i)
        af[i] = *(const bf16x8*)(&As[buf][(wm + i * 16 + lm) * BK + csw]);
#pragma unroll
      for (int j = 0; j < TN; ++j)
        bfr[j] = *(const bf16x8*)(&Bs[buf][(wn + j * 16 + lm) * BK + csw]);
#pragma unroll
      for (int i = 0; i < TM; ++i)
#pragma unroll
        for (int j = 0; j < TN; ++j)
          acc[i][j] = __builtin_amdgcn_mfma_f32_16x16x32_bf16(af[i], bfr[j],
                                                              acc[i][j], 0, 0, 0);
    }
    __syncthreads();  // drains vmcnt: buf^1 fully written, reads complete
  }

  // epilogue: C/D layout col = lane&15, row = kq*4 + r
  float* Pz = P + (size_t)blockIdx.z * BM * N;
#pragma unroll
  for (int i = 0; i < TM; ++i) {
    const int mrow = wm + i * 16 + kq * 4;
#pragma unroll
    for (int j = 0; j < TN; ++j) {
      const int col = n0 + wn + j * 16 + lm;
#pragma unroll
      for (int r = 0; r < 4; ++r)
        Pz[(size_t)(mrow + r) * N + col] = acc[i][j][r];
    }
  }
}

// ---------------------------------------------------------------------------
// out[i] = bf16( sum_{s<4} P[s][i] ), float4-vectorized.
// ---------------------------------------------------------------------------
__global__ __launch_bounds__(256) void reduce4_bf16(const float* __restrict__ P,
                                                    bf16* __restrict__ out,
                                                    size_t MN) {
  const size_t i4 = ((size_t)blockIdx.x * 256 + threadIdx.x) * 4;
  if (i4 >= MN) return;
  f32x4 a = *(const f32x4*)(P + i4);
  f32x4 b = *(const f32x4*)(P + MN + i4);
  f32x4 c = *(const f32x4*)(P + 2 * MN + i4);
  f32x4 d = *(const f32x4*)(P + 3 * MN + i4);
  a = a + b + c + d;
  bf16 o[4] = {(bf16)a[0], (bf16)a[1], (bf16)a[2], (bf16)a[3]};
  *(int2*)(out + i4) = *(const int2*)o;
}

// ---------------------------------------------------------------------------
// 64x64 LDS tile transpose/convert: src [R][C] f32 ->
//   cpy [R][C] bf16 (opt), trb [C][R] bf16 (opt), trf [C][R] f32 (opt),
//   cnt[c] += column sums (opt; used to fuse hyperedge counts into the
//   H transpose - fp32 adds of 0/1 integers are exact & order-independent).
// ---------------------------------------------------------------------------
__global__ __launch_bounds__(256) void transpose_conv(
    const float* __restrict__ src, int R, int C, bf16* __restrict__ cpy,
    bf16* __restrict__ trb, float* __restrict__ trf, float* __restrict__ cnt) {
  __shared__ float tile[64][65];
  __shared__ float cs[4][64];
  const int t = threadIdx.x;
  const int col = t & 63, rb4 = t >> 6;
  const int r0 = blockIdx.y * 64, c0 = blockIdx.x * 64;
  float csum = 0.f;
#pragma unroll
  for (int rr = 0; rr < 64; rr += 4) {
    const int row = rr + rb4;
    const float v = src[(size_t)(r0 + row) * C + c0 + col];
    tile[row][col] = v;
    csum += v;
    if (cpy) cpy[(size_t)(r0 + row) * C + c0 + col] = (bf16)v;
  }
  __syncthreads();
  if (cnt) {
    cs[rb4][col] = csum;
    __syncthreads();
    if (rb4 == 0)
      atomicAdd(&cnt[c0 + col], cs[0][col] + cs[1][col] + cs[2][col] + cs[3][col]);
  }
#pragma unroll
  for (int rr = 0; rr < 64; rr += 4) {
    const int row = rr + rb4;
    const float v = tile[col][row];
    const size_t di = (size_t)(c0 + row) * R + r0 + col;
    if (trb) trb[di] = (bf16)v;
    if (trf) trf[di] = v;
  }
}

// ---------------------------------------------------------------------------
// LayerNorm over d, fused 4-way split-K reduce. block (32 nodes, 8 d-groups)
// ---------------------------------------------------------------------------
__global__ __launch_bounds__(256) void ln_kernel(const float* __restrict__ P,
                                                 const float* __restrict__ x0t,
                                                 const float* __restrict__ gamma,
                                                 const float* __restrict__ beta,
                                                 bf16* __restrict__ Xt) {
  constexpr size_t MN = (size_t)256 * 8192;
  const int tx = threadIdx.x;
  const int ty = threadIdx.y;
  const int i = blockIdx.x * 32 + tx;
  float vbuf[32];
  float s = 0.f, s2 = 0.f;
#pragma unroll
  for (int dd = 0; dd < 32; ++dd) {
    const int d = ty * 32 + dd;
    const size_t idx = (size_t)d * 8192 + i;
    const float v = P[idx] + P[MN + idx] + P[2 * MN + idx] + P[3 * MN + idx] +
                    x0t[idx];
    vbuf[dd] = v;
    s += v;
    s2 += v * v;
  }
  __shared__ float S[8][32], Q[8][32];
  S[ty][tx] = s;
  Q[ty][tx] = s2;
  __syncthreads();
  __shared__ float MU[32], RS[32];
  if (ty == 0) {
    float a = 0.f, b = 0.f;
#pragma unroll
    for (int r = 0; r < 8; ++r) {
      a += S[r][tx];
      b += Q[r][tx];
    }
    const float mu = a * (1.0f / 256.0f);
    const float var = b * (1.0f / 256.0f) - mu * mu;
    MU[tx] = mu;
    RS[tx] = rsqrtf(var + 1e-5f);
  }
  __syncthreads();
  const float mu = MU[tx], rs = RS[tx];
#pragma unroll
  for (int dd = 0; dd < 32; ++dd) {
    const int d = ty * 32 + dd;
    const float y = (vbuf[dd] - mu) * rs * gamma[d] + beta[d];
    Xt[(size_t)d * 8192 + i] = (bf16)y;
  }
}

// ---------------------------------------------------------------------------
// out[d] = max_e (sum_{s<S} P[s][d][e]) / cnt[e]
// ---------------------------------------------------------------------------
__global__ __launch_bounds__(256) void final_max(const float* __restrict__ P,
                                                 const float* __restrict__ cnt,
                                                 float* __restrict__ out,
                                                 int S) {
  constexpr size_t MN = (size_t)256 * 4096;
  const int d = blockIdx.x;
  float m = -3.4e38f;
  for (int e = threadIdx.x; e < 4096; e += 256) {
    const size_t idx = (size_t)d * 4096 + e;
    float s = 0.f;
    for (int z = 0; z < S; ++z) s += P[z * MN + idx];
    m = fmaxf(m, s / cnt[e]);
  }
  __shared__ float red[256];
  red[threadIdx.x] = m;
  __syncthreads();
  for (int k = 128; k > 0; k >>= 1) {
    if (threadIdx.x < k)
      red[threadIdx.x] = fmaxf(red[threadIdx.x], red[threadIdx.x + k]);
    __syncthreads();
  }
  if (threadIdx.x == 0) out[d] = red[0];
}

// ---------------------------------------------------------------------------
extern "C" void kernel_launch(void* const* d_in, const int* in_sizes, int n_in,
                              void* d_out, int out_size, void* d_ws,
                              size_t ws_size, hipStream_t stream) {
  const float* x0 = (const float*)d_in[0];    // [8192][256]
  const float* T = (const float*)d_in[1];     // [8192][8192]
  const float* H = (const float*)d_in[2];     // [8192][4096]
  const float* gamma = (const float*)d_in[3]; // [256]
  const float* beta = (const float*)d_in[4];  // [256]

  constexpr int Nn = 8192, E = 4096, D = 256, K = 8192;

  char* w = (char*)d_ws;
  size_t off = 0;
  auto carve = [&](size_t bytes) {
    char* p = w + off;
    off += (bytes + 255) & ~(size_t)255;
    return p;
  };
  bf16* Tb = (bf16*)carve((size_t)Nn * Nn * 2);
  bf16* Tt = (bf16*)carve((size_t)Nn * Nn * 2);
  bf16* Htb = (bf16*)carve((size_t)E * Nn * 2);
  float* x0t = (float*)carve((size_t)D * Nn * 4);
  bf16* Xt = (bf16*)carve((size_t)D * Nn * 2);
  bf16* tt = (bf16*)carve((size_t)D * Nn * 2);
  bf16* stb = (bf16*)carve((size_t)D * Nn * 2);
  float* cnts = (float*)carve((size_t)E * 4);
  float* P = (float*)carve((size_t)4 * D * Nn * 4);  // 32 MB partials

  if (off > ws_size) {  // workspace too small: fail loudly (out = 0)
    hipMemsetAsync(d_out, 0, (size_t)out_size * 4, stream);
    return;
  }

  // one-time layout prep (counts fused into the H transpose)
  hipMemsetAsync(cnts, 0, (size_t)E * 4, stream);
  transpose_conv<<<dim3(128, 128), 256, 0, stream>>>(T, Nn, Nn, Tb, Tt, nullptr,
                                                     nullptr);
  transpose_conv<<<dim3(64, 128), 256, 0, stream>>>(H, Nn, E, nullptr, Htb,
                                                    nullptr, cnts);
  transpose_conv<<<dim3(4, 128), 256, 0, stream>>>(x0, Nn, D, nullptr, Xt, x0t,
                                                   nullptr);

  const size_t MN = (size_t)D * Nn;
  for (int layer = 0; layer < 3; ++layer) {
    // P = split-K partials of  tt[d][j] = sum_k Xt[d][k] * Tb[j][k]
    gemm_bt<64><<<dim3(128, 1, 4), 512, 0, stream>>>(Xt, Tb, P, Nn, K, K / 4);
    reduce4_bf16<<<(int)(MN / 1024), 256, 0, stream>>>(P, tt, MN);
    // P = split-K partials of  st[d][i] = sum_j tt[d][j] * Tt[i][j]
    gemm_bt<64><<<dim3(128, 1, 4), 512, 0, stream>>>(tt, Tt, P, Nn, K, K / 4);
    if (layer < 2) {
      ln_kernel<<<dim3(256), dim3(32, 8), 0, stream>>>(P, x0t, gamma, beta, Xt);
    } else {
      reduce4_bf16<<<(int)(MN / 1024), 256, 0, stream>>>(P, stb, MN);
    }
  }

  // P = split-K(8) partials of  sumsT[d][e] = sum_i stb[d][i] * Htb[e][i]
  gemm_bt<64><<<dim3(64, 1, 8), 512, 0, stream>>>(stb, Htb, P, E, K, K / 8);
  final_max<<<D, 256, 0, stream>>>(P, cnts, (float*)d_out, 8);
}